// Round 8
// baseline (475.356 us; speedup 1.0000x reference)
//
#include <hip/hip_runtime.h>
#include <math.h>
#include <stdint.h>

#define NN 50000
#define NE 800000
#define HD 64
#define ECH 32
#define NHEAD 4
#define NBLK 196   // ceil(NN/256)
#define NEBLK (NE / 256)

static_assert(NE % 256 == 0, "edge kernel assumes full blocks");

typedef __attribute__((ext_vector_type(8))) short bf8;
typedef __attribute__((ext_vector_type(4))) float f32x4;
typedef __attribute__((ext_vector_type(2))) float v2f;
typedef __attribute__((ext_vector_type(2))) __bf16 v2bf;

#define LOG2E 1.44269504088896340736f
#define LN2   0.69314718055994530942f

// softplus(v) - ln2 via NATIVE v_exp_f32 / v_log_f32 (log2 domain).
__device__ __forceinline__ float ssp_f(float v) {
    float t = __builtin_amdgcn_exp2f(-fabsf(v) * LOG2E);
    return fmaxf(v, 0.0f) + LN2 * __builtin_amdgcn_logf(1.0f + t) - LN2;
}
__device__ __forceinline__ float bf2f(uint32_t b) { return __uint_as_float(b << 16); }

// f32 pair -> packed 2x bf16 (RNE). Lowers to v_cvt_pk_bf16_f32 on gfx950.
__device__ __forceinline__ uint32_t cvt_pk_bf16(float lo, float hi) {
    v2f v = {lo, hi};
    v2bf b = __builtin_convertvector(v, v2bf);
    return __builtin_bit_cast(uint32_t, b);
}
// packed 2x bf16 -> f32 pair (feeds v_pk_* packed math)
__device__ __forceinline__ v2f bfpair(uint32_t p) {
    v2f r;
    r.x = __uint_as_float(p << 16);
    r.y = __uint_as_float(p & 0xffff0000u);
    return r;
}
__device__ __forceinline__ uint4 pack8c(const float* s) {
    uint4 r;
    r.x = cvt_pk_bf16(s[0], s[1]);
    r.y = cvt_pk_bf16(s[2], s[3]);
    r.z = cvt_pk_bf16(s[4], s[5]);
    r.w = cvt_pk_bf16(s[6], s[7]);
    return r;
}
__device__ __forceinline__ bf8 pack_bf8(float4 a, float4 b) {
    union { uint32_t u[4]; bf8 v; } r;
    r.u[0] = cvt_pk_bf16(a.x, a.y);
    r.u[1] = cvt_pk_bf16(a.z, a.w);
    r.u[2] = cvt_pk_bf16(b.x, b.y);
    r.u[3] = cvt_pk_bf16(b.z, b.w);
    return r.v;
}
__device__ __forceinline__ bf8 zero_bf8() {
    bf8 r;
    #pragma unroll
    for (int i = 0; i < 8; ++i) r[i] = 0;
    return r;
}

// ---------------- Kernel A (merged): edge count + node q/k/v transform ----------------
// qtq[n]: 72 uint16 = 64 bf16 qt | 4 f32 qb  (qt/qb PRE-SCALED by log2e so the
//         edge kernel's softmax weight is a single native v_exp_f32)
// hkv[n]: 128 uint16 = 64 bf16 k | 64 bf16 v (one 256B row)
__global__ __launch_bounds__(256) void node_count_kernel(
    const float* __restrict__ x, const int* __restrict__ ei,
    const float* __restrict__ k_w, const float* __restrict__ q_w, const float* __restrict__ v_w,
    const float* __restrict__ wkl_w, const float* __restrict__ wkl_b,
    uint16_t* __restrict__ qtq, uint16_t* __restrict__ hkv,
    int* __restrict__ counts)
{
    // --- count part: every block covers 256 edges (grid = NE/256 >= NBLK) ---
    atomicAdd(counts + ei[blockIdx.x * 256 + threadIdx.x], 1);

    // --- node part: first NBLK blocks ---
    if (blockIdx.x >= NBLK) return;
    __shared__ float skw[NHEAD * 256], sqw[NHEAD * 256], svw[NHEAD * 256];
    __shared__ float s_kl[256], s_klb[16];
    for (int i = threadIdx.x; i < NHEAD * 256; i += 256) {
        skw[i] = k_w[i]; sqw[i] = q_w[i]; svw[i] = v_w[i];
    }
    // fold log2e into the wkl transform (exp(qk) == exp2(qk') downstream)
    if (threadIdx.x < 256) s_kl[threadIdx.x] = wkl_w[threadIdx.x] * LOG2E;
    if (threadIdx.x < 16) s_klb[threadIdx.x] = wkl_b[threadIdx.x] * LOG2E;
    __syncthreads();
    int n = blockIdx.x * 256 + threadIdx.x;
    if (n >= NN) return;
    const float* xn = x + (size_t)n * HD;
    uint16_t* qrow = qtq + (size_t)n * 72;
    uint16_t* kvrow = hkv + (size_t)n * 128;
    float qbv[NHEAD];
    for (int h = 0; h < NHEAD; ++h) {
        v2f xr2[8];
        {
            const float4* xp = (const float4*)(xn + h * 16);
            #pragma unroll
            for (int j = 0; j < 4; ++j) {
                float4 t4 = xp[j];
                xr2[2 * j] = (v2f){t4.x, t4.y};
                xr2[2 * j + 1] = (v2f){t4.z, t4.w};
            }
        }
        float rq[16], rk[16], rv[16];
        for (int o = 0; o < 16; ++o) {
            const v2f* wq = (const v2f*)(sqw + h * 256 + o * 16);
            const v2f* wk = (const v2f*)(skw + h * 256 + o * 16);
            const v2f* wv = (const v2f*)(svw + h * 256 + o * 16);
            v2f sq = {0.f, 0.f}, sk = {0.f, 0.f}, sv = {0.f, 0.f};
            #pragma unroll
            for (int j = 0; j < 8; ++j) {
                sq += xr2[j] * wq[j];
                sk += xr2[j] * wk[j];
                sv += xr2[j] * wv[j];
            }
            rq[o] = sq.x + sq.y; rk[o] = sk.x + sk.y; rv[o] = sv.x + sv.y;
        }
        // rqt[i] = sum_o rq[o] * wkl'[o][i]   (paired over i -> v_pk_fma_f32)
        float rqt[16];
        #pragma unroll
        for (int ip = 0; ip < 8; ++ip) {
            v2f s2 = {0.f, 0.f};
            #pragma unroll
            for (int o = 0; o < 16; ++o) {
                v2f kl = *(const v2f*)(s_kl + o * 16 + 2 * ip);
                v2f q2 = {rq[o], rq[o]};
                s2 += q2 * kl;
            }
            rqt[2 * ip] = s2.x; rqt[2 * ip + 1] = s2.y;
        }
        float qbh = 0.f;
        #pragma unroll
        for (int o = 0; o < 16; ++o) qbh += rq[o] * s_klb[o];
        qbv[h] = qbh;

        uint4* oq = (uint4*)(qrow + h * 16);
        uint4* ok = (uint4*)(kvrow + h * 16);
        uint4* ov = (uint4*)(kvrow + 64 + h * 16);
        oq[0] = pack8c(rqt); oq[1] = pack8c(rqt + 8);
        ok[0] = pack8c(rk);  ok[1] = pack8c(rk + 8);
        ov[0] = pack8c(rv);  ov[1] = pack8c(rv + 8);
    }
    *(float4*)(qrow + 64) = *(float4*)&qbv[0];
}

// ---------------- Hierarchical scan ----------------
__global__ __launch_bounds__(256) void scan_bsum_kernel(
    const int* __restrict__ counts, int* __restrict__ bsum)
{
    __shared__ int sd[256];
    int i = blockIdx.x * 256 + threadIdx.x;
    sd[threadIdx.x] = (i < NN) ? counts[i] : 0;
    __syncthreads();
    for (int s = 128; s > 0; s >>= 1) {
        if (threadIdx.x < (unsigned)s) sd[threadIdx.x] += sd[threadIdx.x + s];
        __syncthreads();
    }
    if (threadIdx.x == 0) bsum[blockIdx.x] = sd[0];
}

__global__ __launch_bounds__(256) void scan_top_kernel(int* __restrict__ bsum)
{
    __shared__ int tmp[256];
    int v = (threadIdx.x < NBLK) ? bsum[threadIdx.x] : 0;
    tmp[threadIdx.x] = v;
    __syncthreads();
    for (int d = 1; d < 256; d <<= 1) {
        int t = (threadIdx.x >= (unsigned)d) ? tmp[threadIdx.x - d] : 0;
        __syncthreads();
        tmp[threadIdx.x] += t;
        __syncthreads();
    }
    if (threadIdx.x < NBLK) bsum[threadIdx.x] = tmp[threadIdx.x] - v;  // exclusive
}

__global__ __launch_bounds__(256) void scan_final_kernel(
    const int* __restrict__ counts, const int* __restrict__ bsum,
    int* __restrict__ offsets, int* __restrict__ cursor)
{
    __shared__ int tmp[256];
    int i = blockIdx.x * 256 + threadIdx.x;
    int v = (i < NN) ? counts[i] : 0;
    tmp[threadIdx.x] = v;
    __syncthreads();
    for (int d = 1; d < 256; d <<= 1) {
        int t = (threadIdx.x >= (unsigned)d) ? tmp[threadIdx.x - d] : 0;
        __syncthreads();
        tmp[threadIdx.x] += t;
        __syncthreads();
    }
    int excl = tmp[threadIdx.x] - v + bsum[blockIdx.x];
    if (i < NN) { offsets[i] = excl; cursor[i] = excl; }
}

// ---------------- Scatter: (edge id, packed row|col) as ONE uint2 into CSR order ----------------
__global__ __launch_bounds__(256) void scatter_kernel(
    const int* __restrict__ ei, int* __restrict__ cursor,
    uint2* __restrict__ evec)
{
    int e = blockIdx.x * 256 + threadIdx.x;
    if (e >= NE) return;
    int r = ei[e];
    int c = ei[NE + e];
    int pos = atomicAdd(cursor + r, 1);
    evec[pos] = make_uint2((uint32_t)e, ((uint32_t)r << 16) | (uint32_t)c);
}

// ---------------- Kernel B: edge compute, MFMA MLPs, merged layer2+tail ----------------
// s_trB eliminated (LDS 24.6KB -> 12.3KB): layer2-k result is read back into regs
// BEFORE layer2-v overwrites the same LDS rows (same-wave in-order DS pipe, the
// R4-validated pattern). Tail's 6 random 16B loads are issued at the TOP of each
// tile iteration so their latency hides under the MFMA+LDS chain.
__global__ __launch_bounds__(256) void edge_compute_kernel(
    const uint2* __restrict__ evec,
    const float* __restrict__ ea,
    const float* __restrict__ wkn_w1, const float* __restrict__ wkn_b1,
    const float* __restrict__ wkn_w2, const float* __restrict__ wkn_b2,
    const float* __restrict__ wvn_w1, const float* __restrict__ wvn_b1,
    const float* __restrict__ wvn_w2, const float* __restrict__ wvn_b2,
    const uint16_t* __restrict__ qtq, const uint16_t* __restrict__ hkv,
    uint16_t* __restrict__ payload, float* __restrict__ wfac)
{
    // per-wave PRIVATE LDS, no barriers (same-wave in-order DS pipe).
    __shared__ uint16_t s_trA[4][64][24];   // 12.3KB total

    const int w = threadIdx.x >> 6;
    const int L = threadIdx.x & 63;
    const int m = L & 15;     // MFMA: A out-ch / B edge; tail: edge-within-tile
    const int g = L >> 4;     // MFMA: k-group; tail: head
    const int ebase = blockIdx.x * 256 + w * 64;

    // prefetch (edge id, row|col) for the 4 tiles — single 8B stream
    int eidv[4];
    uint32_t rcv[4];
    #pragma unroll
    for (int t = 0; t < 4; ++t) {
        uint2 ev = evec[ebase + 16 * t + m];
        eidv[t] = (int)ev.x;
        rcv[t] = ev.y;
    }

    // --- stage edge_attr B-fragments: B[k=8g+j][n=m] = ea[edge 16t+m][8g+j] ---
    bf8 eaf[4];
    #pragma unroll
    for (int t = 0; t < 4; ++t) {
        const float* er = ea + (size_t)eidv[t] * ECH + 8 * g;
        eaf[t] = pack_bf8(*(const float4*)er, *(const float4*)(er + 4));
    }
    // --- weight A-fragments ---
    bf8 w1kf, w1vf, w2kf, w2vf;
    {
        const float* p = wkn_w1 + m * 32 + 8 * g;
        w1kf = pack_bf8(*(const float4*)p, *(const float4*)(p + 4));
        p = wvn_w1 + m * 32 + 8 * g;
        w1vf = pack_bf8(*(const float4*)p, *(const float4*)(p + 4));
        if (g < 2) {
            p = wkn_w2 + m * 16 + 8 * g;
            w2kf = pack_bf8(*(const float4*)p, *(const float4*)(p + 4));
            p = wvn_w2 + m * 16 + 8 * g;
            w2vf = pack_bf8(*(const float4*)p, *(const float4*)(p + 4));
        } else {
            w2kf = zero_bf8(); w2vf = zero_bf8();
        }
    }
    float4 b1k = *(const float4*)(wkn_b1 + 4 * g);
    float4 b1v = *(const float4*)(wvn_b1 + 4 * g);
    float4 b2k = *(const float4*)(wkn_b2 + 4 * g);
    float4 b2v = *(const float4*)(wvn_b2 + 4 * g);

    // --- layer1 k-net -> s_trA; read l1k ---
    #pragma unroll
    for (int t = 0; t < 4; ++t) {
        f32x4 acc = {b1k.x, b1k.y, b1k.z, b1k.w};
        acc = __builtin_amdgcn_mfma_f32_16x16x32_bf16(w1kf, eaf[t], acc, 0, 0, 0);
        uint2 pk;
        pk.x = cvt_pk_bf16(ssp_f(acc[0]), ssp_f(acc[1]));
        pk.y = cvt_pk_bf16(ssp_f(acc[2]), ssp_f(acc[3]));
        *(uint2*)&s_trA[w][16 * t + m][4 * g] = pk;
    }
    bf8 l1k[4];
    #pragma unroll
    for (int t = 0; t < 4; ++t)
        l1k[t] = (g < 2) ? *(const bf8*)&s_trA[w][16 * t + m][8 * g] : zero_bf8();
    // --- layer1 v-net -> s_trA (reuse); read l1v ---
    #pragma unroll
    for (int t = 0; t < 4; ++t) {
        f32x4 acc = {b1v.x, b1v.y, b1v.z, b1v.w};
        acc = __builtin_amdgcn_mfma_f32_16x16x32_bf16(w1vf, eaf[t], acc, 0, 0, 0);
        uint2 pk;
        pk.x = cvt_pk_bf16(ssp_f(acc[0]), ssp_f(acc[1]));
        pk.y = cvt_pk_bf16(ssp_f(acc[2]), ssp_f(acc[3]));
        *(uint2*)&s_trA[w][16 * t + m][4 * g] = pk;
    }
    bf8 l1v[4];
    #pragma unroll
    for (int t = 0; t < 4; ++t)
        l1v[t] = (g < 2) ? *(const bf8*)&s_trA[w][16 * t + m][8 * g] : zero_bf8();

    // --- merged layer2 + tail, one tile at a time ---
    #pragma unroll
    for (int t = 0; t < 4; ++t) {
        const int E = ebase + 16 * t + m;
        const int row = (int)(rcv[t] >> 16), col = (int)(rcv[t] & 0xffffu);

        // issue the random q/k/v loads FIRST: latency hides under the MFMA+LDS chain
        const uint16_t* qrow = qtq + (size_t)row * 72;
        const uint16_t* kvrow = hkv + (size_t)col * 128;
        uint32_t q_u[8], k_u[8], v_u[8];
        *(uint4*)&q_u[0] = *(const uint4*)(qrow + 16 * g);
        *(uint4*)&q_u[4] = *(const uint4*)(qrow + 16 * g + 8);
        *(uint4*)&k_u[0] = *(const uint4*)(kvrow + 16 * g);
        *(uint4*)&k_u[4] = *(const uint4*)(kvrow + 16 * g + 8);
        *(uint4*)&v_u[0] = *(const uint4*)(kvrow + 64 + 16 * g);
        *(uint4*)&v_u[4] = *(const uint4*)(kvrow + 64 + 16 * g + 8);
        const float qb = *(const float*)(qrow + 64 + 2 * g);

        // layer2-k: MFMA -> LDS -> wk_u regs
        f32x4 acc = {b2k.x, b2k.y, b2k.z, b2k.w};
        acc = __builtin_amdgcn_mfma_f32_16x16x32_bf16(w2kf, l1k[t], acc, 0, 0, 0);
        uint2 pk;
        pk.x = cvt_pk_bf16(acc[0], acc[1]);
        pk.y = cvt_pk_bf16(acc[2], acc[3]);
        *(uint2*)&s_trA[w][16 * t + m][4 * g] = pk;
        uint32_t wk_u[8];
        *(uint4*)&wk_u[0] = *(const uint4*)&s_trA[w][16 * t + m][0];
        *(uint4*)&wk_u[4] = *(const uint4*)&s_trA[w][16 * t + m][8];

        // layer2-v: MFMA -> LDS (overwrite same rows; read above is in-order-before) -> wv_u
        f32x4 accv = {b2v.x, b2v.y, b2v.z, b2v.w};
        accv = __builtin_amdgcn_mfma_f32_16x16x32_bf16(w2vf, l1v[t], accv, 0, 0, 0);
        uint2 pv;
        pv.x = cvt_pk_bf16(accv[0], accv[1]);
        pv.y = cvt_pk_bf16(accv[2], accv[3]);
        *(uint2*)&s_trA[w][16 * t + m][4 * g] = pv;
        uint32_t wv_u[8];
        *(uint4*)&wv_u[0] = *(const uint4*)&s_trA[w][16 * t + m][0];
        *(uint4*)&wv_u[4] = *(const uint4*)&s_trA[w][16 * t + m][8];

        // tail math: packed-f32 + single native v_exp_f32 (log2e pre-folded)
        v2f qk2 = {0.f, 0.f};
        #pragma unroll
        for (int i = 0; i < 8; ++i)
            qk2 += bfpair(q_u[i]) * (bfpair(wk_u[i]) * bfpair(k_u[i]));
        float qk = qb + qk2.x + qk2.y;
        float wgt = __builtin_amdgcn_exp2f(qk);   // == exp(true logit)
        v2f wgt2 = {wgt, wgt};

        uint32_t po[8];
        #pragma unroll
        for (int i = 0; i < 8; ++i) {
            v2f o2 = (bfpair(wv_u[i]) * bfpair(v_u[i])) * wgt2;
            po[i] = cvt_pk_bf16(o2.x, o2.y);
        }
        uint4* pd = (uint4*)(payload + (size_t)E * HD + 16 * g);
        pd[0] = *(uint4*)&po[0];
        pd[1] = *(uint4*)&po[4];
        wfac[(size_t)E * NHEAD + g] = wgt;   // contiguous 256B per instr
    }
}

// ---------------- Kernel G: pure gather+normalize, one wave per node ----------------
// 50000 waves, zero LDS, ~30 VGPR -> full occupancy; CSR-contiguous payload streaming.
__global__ __launch_bounds__(256) void gather_kernel(
    const uint16_t* __restrict__ payload, const float* __restrict__ wfac,
    const int* __restrict__ offsets, const int* __restrict__ counts,
    float* __restrict__ mout)
{
    const int n = (blockIdx.x * 256 + threadIdx.x) >> 6;   // one wave per node
    if (n >= NN) return;
    const int L = threadIdx.x & 63;
    const int q = L & 7;              // channel octet
    const int g = L >> 3;             // edge group 0..7
    const int h = q >> 1;             // head owning the octet

    const int st = offsets[n];
    const int deg = counts[n];

    v2f u2[4] = {{0.f,0.f},{0.f,0.f},{0.f,0.f},{0.f,0.f}};
    float ds = 0.f;
    const uint16_t* pp = payload + (size_t)st * HD + 8 * q;
    const float* wp = wfac + (size_t)st * NHEAD + h;
    const int iters = (deg + 7) >> 3;
    for (int i = 0; i < iters; i += 2) {
        // two independent 1KB wave-loads in flight per pass (R4-measured config)
        const int e0 = 8 * i + g;
        const int e1 = e0 + 8;
        if (e0 < deg) {
            uint4 pv = *(const uint4*)(pp + (size_t)e0 * HD);
            u2[0] += bfpair(pv.x); u2[1] += bfpair(pv.y);
            u2[2] += bfpair(pv.z); u2[3] += bfpair(pv.w);
            ds += wp[(size_t)e0 * NHEAD];
        }
        if (e1 < deg) {
            uint4 pv = *(const uint4*)(pp + (size_t)e1 * HD);
            u2[0] += bfpair(pv.x); u2[1] += bfpair(pv.y);
            u2[2] += bfpair(pv.z); u2[3] += bfpair(pv.w);
            ds += wp[(size_t)e1 * NHEAD];
        }
    }
    // reduce over the 8 edge-groups (xor lane bits 3,4,5)
    #pragma unroll
    for (int s = 8; s < 64; s <<= 1) {
        #pragma unroll
        for (int j = 0; j < 4; ++j) {
            u2[j].x += __shfl_xor(u2[j].x, s);
            u2[j].y += __shfl_xor(u2[j].y, s);
        }
        ds += __shfl_xor(ds, s);
    }
    if (g == 0) {
        float inv = (deg > 0) ? (1.f / ds) : 0.f;
        float r0[4] = {u2[0].x * inv, u2[0].y * inv, u2[1].x * inv, u2[1].y * inv};
        float r1[4] = {u2[2].x * inv, u2[2].y * inv, u2[3].x * inv, u2[3].y * inv};
        float* mr = mout + (size_t)n * HD + 8 * q;
        *(float4*)mr = *(float4*)r0;
        *(float4*)(mr + 4) = *(float4*)r1;
    }
}

// ---------------- Kernel F: dense finalize (wvl + cen + ssp + out) ----------------
__global__ __launch_bounds__(256) void finalize_kernel(
    const float* __restrict__ x, const float* __restrict__ m,
    const int* __restrict__ counts,
    const float* __restrict__ wvl_w, const float* __restrict__ wvl_b,
    const float* __restrict__ cen_w, const float* __restrict__ cen_b,
    const float* __restrict__ out_w, const float* __restrict__ out_b,
    float* __restrict__ out)
{
    __shared__ float s_cw[4096], s_ow[4096];
    __shared__ float s_x[4][64], s_m[4][64], s_t[4][64];
    for (int idx = threadIdx.x; idx < 4096; idx += 256) {
        int o = idx & 63, i = idx >> 6;
        s_cw[i * 64 + o] = cen_w[o * 64 + i];
        s_ow[i * 64 + o] = out_w[o * 64 + i];
    }
    __syncthreads();

    const int l = threadIdx.x >> 6;   // wave id
    const int c = threadIdx.x & 63;   // lane = output channel
    const int hh = c >> 4;

    // hoisted per-lane constants (channel is fixed per lane)
    float wvlr[16];
    #pragma unroll
    for (int i = 0; i < 16; ++i) wvlr[i] = wvl_w[(c & 15) * 16 + i];
    const float vlb = wvl_b[c & 15];
    const float cb = cen_b[c];
    const float ob = out_b[c];

    const int n0 = blockIdx.x * 64 + l * 16;
    for (int t = 0; t < 16; ++t) {
        const int n = n0 + t;
        const bool valid = n < NN;
        const int deg = valid ? counts[n] : 0;
        s_x[l][c] = valid ? x[(size_t)n * HD + c] : 0.f;
        s_m[l][c] = valid ? m[(size_t)n * HD + c] : 0.f;
        // s_x/s_m/s_t rows are same-wave private: no __syncthreads needed

        float aggr = 0.f;
        if (deg > 0) {
            float s = vlb;
            #pragma unroll
            for (int i = 0; i < 16; ++i) s += s_m[l][hh * 16 + i] * wvlr[i];
            aggr = s;
        }
        float sc = cb;
        #pragma unroll 8
        for (int i = 0; i < 64; ++i) sc += s_x[l][i] * s_cw[i * 64 + c];
        sc += aggr;
        s_t[l][c] = ssp_f(sc);
        float so = ob;
        #pragma unroll 8
        for (int i = 0; i < 64; ++i) so += s_t[l][i] * s_ow[i * 64 + c];
        if (valid) out[(size_t)n * HD + c] = so;
    }
}

extern "C" void kernel_launch(void* const* d_in, const int* in_sizes, int n_in,
                              void* d_out, int out_size, void* d_ws, size_t ws_size,
                              hipStream_t stream)
{
    const float* x      = (const float*)d_in[0];
    const int*   ei     = (const int*)d_in[1];
    const float* ea     = (const float*)d_in[2];
    const float* k_w    = (const float*)d_in[3];
    const float* q_w    = (const float*)d_in[4];
    const float* v_w    = (const float*)d_in[5];
    const float* wkn_w1 = (const float*)d_in[6];
    const float* wkn_b1 = (const float*)d_in[7];
    const float* wkn_w2 = (const float*)d_in[8];
    const float* wkn_b2 = (const float*)d_in[9];
    const float* wkl_w  = (const float*)d_in[10];
    const float* wkl_b  = (const float*)d_in[11];
    const float* wvn_w1 = (const float*)d_in[12];
    const float* wvn_b1 = (const float*)d_in[13];
    const float* wvn_w2 = (const float*)d_in[14];
    const float* wvn_b2 = (const float*)d_in[15];
    const float* wvl_w  = (const float*)d_in[16];
    const float* wvl_b  = (const float*)d_in[17];
    const float* cen_w  = (const float*)d_in[18];
    const float* cen_b  = (const float*)d_in[19];
    const float* out_w  = (const float*)d_in[20];
    const float* out_b  = (const float*)d_in[21];
    float* out = (float*)d_out;

    // workspace layout
    float* wfac  = (float*)d_ws;                              // NE*4 f32
    uint16_t* qtq = (uint16_t*)(wfac + (size_t)NE * NHEAD);   // NN*72 (qt bf16 | qb f32)
    uint16_t* hkv = qtq + (size_t)NN * 72;                    // NN*128 (k|v bf16)
    uint16_t* payload = hkv + (size_t)NN * 128;               // NE*64 bf16
    uint2* evec  = (uint2*)(payload + (size_t)NE * HD);       // NE (eid, r<<16|c)
    int* counts  = (int*)(evec + (size_t)NE);                 // NN
    int* bsum    = counts + NN;                               // 256
    int* offsets = bsum + 256;                                // NN
    int* cursor  = offsets + NN;                              // NN
    // m buffer aliases hkv (dead after edge_compute; NN*128 u16 == NN*64 f32)
    float* mbuf  = (float*)hkv;

    hipMemsetAsync(counts, 0, (size_t)NN * sizeof(int), stream);
    node_count_kernel<<<NEBLK, 256, 0, stream>>>(
        x, ei, k_w, q_w, v_w, wkl_w, wkl_b, qtq, hkv, counts);
    scan_bsum_kernel<<<NBLK, 256, 0, stream>>>(counts, bsum);
    scan_top_kernel<<<1, 256, 0, stream>>>(bsum);
    scan_final_kernel<<<NBLK, 256, 0, stream>>>(counts, bsum, offsets, cursor);
    scatter_kernel<<<NEBLK, 256, 0, stream>>>(ei, cursor, evec);
    edge_compute_kernel<<<NEBLK, 256, 0, stream>>>(
        evec, ea, wkn_w1, wkn_b1, wkn_w2, wkn_b2,
        wvn_w1, wvn_b1, wvn_w2, wvn_b2,
        qtq, hkv, payload, wfac);
    gather_kernel<<<(NN * 64) / 256, 256, 0, stream>>>(
        payload, wfac, offsets, counts, mbuf);
    finalize_kernel<<<(NN + 63) / 64, 256, 0, stream>>>(
        x, mbuf, counts, wvl_w, wvl_b, cen_w, cen_b, out_w, out_b, out);
}

// Round 9
// 448.553 us; speedup vs baseline: 1.0598x; 1.0598x over previous
//
#include <hip/hip_runtime.h>
#include <math.h>
#include <stdint.h>

#define NN 50000
#define NE 800000
#define HD 64
#define ECH 32
#define NHEAD 4
#define NBLK 196   // ceil(NN/256)
#define NEBLK (NE / 256)

static_assert(NE % 256 == 0, "edge kernel assumes full blocks");

typedef __attribute__((ext_vector_type(8))) short bf8;
typedef __attribute__((ext_vector_type(4))) float f32x4;
typedef __attribute__((ext_vector_type(2))) float v2f;
typedef __attribute__((ext_vector_type(2))) __bf16 v2bf;

#define LOG2E 1.44269504088896340736f
#define LN2   0.69314718055994530942f

// softplus(v) - ln2 via NATIVE v_exp_f32 / v_log_f32 (log2 domain).
__device__ __forceinline__ float ssp_f(float v) {
    float t = __builtin_amdgcn_exp2f(-fabsf(v) * LOG2E);
    return fmaxf(v, 0.0f) + LN2 * __builtin_amdgcn_logf(1.0f + t) - LN2;
}
__device__ __forceinline__ float bf2f(uint32_t b) { return __uint_as_float(b << 16); }

// f32 pair -> packed 2x bf16 (RNE). Lowers to v_cvt_pk_bf16_f32 on gfx950.
__device__ __forceinline__ uint32_t cvt_pk_bf16(float lo, float hi) {
    v2f v = {lo, hi};
    v2bf b = __builtin_convertvector(v, v2bf);
    return __builtin_bit_cast(uint32_t, b);
}
// packed 2x bf16 -> f32 pair (feeds v_pk_* packed math)
__device__ __forceinline__ v2f bfpair(uint32_t p) {
    v2f r;
    r.x = __uint_as_float(p << 16);
    r.y = __uint_as_float(p & 0xffff0000u);
    return r;
}
__device__ __forceinline__ uint4 pack8c(const float* s) {
    uint4 r;
    r.x = cvt_pk_bf16(s[0], s[1]);
    r.y = cvt_pk_bf16(s[2], s[3]);
    r.z = cvt_pk_bf16(s[4], s[5]);
    r.w = cvt_pk_bf16(s[6], s[7]);
    return r;
}
__device__ __forceinline__ bf8 pack_bf8(float4 a, float4 b) {
    union { uint32_t u[4]; bf8 v; } r;
    r.u[0] = cvt_pk_bf16(a.x, a.y);
    r.u[1] = cvt_pk_bf16(a.z, a.w);
    r.u[2] = cvt_pk_bf16(b.x, b.y);
    r.u[3] = cvt_pk_bf16(b.z, b.w);
    return r.v;
}
__device__ __forceinline__ bf8 zero_bf8() {
    bf8 r;
    #pragma unroll
    for (int i = 0; i < 8; ++i) r[i] = 0;
    return r;
}

// ---------------- Kernel A (merged): edge count+RANK + node q/k/v transform ----------------
// rank[e] = atomicAdd return — the edge's position within its row. This replaces the
// entire scatter pass: final CSR position = offsets[row] + rank[e].
// qtq[n]: 72 uint16 = 64 bf16 qt | 4 f32 qb (pre-scaled by log2e -> edge weight is one v_exp_f32)
// hkv[n]: 128 uint16 = 64 bf16 k | 64 bf16 v
__global__ __launch_bounds__(256) void node_count_kernel(
    const float* __restrict__ x, const int* __restrict__ ei,
    const float* __restrict__ k_w, const float* __restrict__ q_w, const float* __restrict__ v_w,
    const float* __restrict__ wkl_w, const float* __restrict__ wkl_b,
    uint16_t* __restrict__ qtq, uint16_t* __restrict__ hkv,
    int* __restrict__ counts, int* __restrict__ rank)
{
    // --- count+rank part: every block covers 256 edges (grid = NE/256 >= NBLK) ---
    {
        int e = blockIdx.x * 256 + threadIdx.x;
        int r = ei[e];
        rank[e] = atomicAdd(counts + r, 1);   // rank within row, free byproduct of counting
    }

    // --- node part: first NBLK blocks ---
    if (blockIdx.x >= NBLK) return;
    __shared__ float skw[NHEAD * 256], sqw[NHEAD * 256], svw[NHEAD * 256];
    __shared__ float s_kl[256], s_klb[16];
    for (int i = threadIdx.x; i < NHEAD * 256; i += 256) {
        skw[i] = k_w[i]; sqw[i] = q_w[i]; svw[i] = v_w[i];
    }
    // fold log2e into the wkl transform (exp(qk) == exp2(qk') downstream)
    if (threadIdx.x < 256) s_kl[threadIdx.x] = wkl_w[threadIdx.x] * LOG2E;
    if (threadIdx.x < 16) s_klb[threadIdx.x] = wkl_b[threadIdx.x] * LOG2E;
    __syncthreads();
    int n = blockIdx.x * 256 + threadIdx.x;
    if (n >= NN) return;
    const float* xn = x + (size_t)n * HD;
    uint16_t* qrow = qtq + (size_t)n * 72;
    uint16_t* kvrow = hkv + (size_t)n * 128;
    float qbv[NHEAD];
    for (int h = 0; h < NHEAD; ++h) {
        v2f xr2[8];
        {
            const float4* xp = (const float4*)(xn + h * 16);
            #pragma unroll
            for (int j = 0; j < 4; ++j) {
                float4 t4 = xp[j];
                xr2[2 * j] = (v2f){t4.x, t4.y};
                xr2[2 * j + 1] = (v2f){t4.z, t4.w};
            }
        }
        float rq[16], rk[16], rv[16];
        for (int o = 0; o < 16; ++o) {
            const v2f* wq = (const v2f*)(sqw + h * 256 + o * 16);
            const v2f* wk = (const v2f*)(skw + h * 256 + o * 16);
            const v2f* wv = (const v2f*)(svw + h * 256 + o * 16);
            v2f sq = {0.f, 0.f}, sk = {0.f, 0.f}, sv = {0.f, 0.f};
            #pragma unroll
            for (int j = 0; j < 8; ++j) {
                sq += xr2[j] * wq[j];
                sk += xr2[j] * wk[j];
                sv += xr2[j] * wv[j];
            }
            rq[o] = sq.x + sq.y; rk[o] = sk.x + sk.y; rv[o] = sv.x + sv.y;
        }
        // rqt[i] = sum_o rq[o] * wkl'[o][i]   (paired over i -> v_pk_fma_f32)
        float rqt[16];
        #pragma unroll
        for (int ip = 0; ip < 8; ++ip) {
            v2f s2 = {0.f, 0.f};
            #pragma unroll
            for (int o = 0; o < 16; ++o) {
                v2f kl = *(const v2f*)(s_kl + o * 16 + 2 * ip);
                v2f q2 = {rq[o], rq[o]};
                s2 += q2 * kl;
            }
            rqt[2 * ip] = s2.x; rqt[2 * ip + 1] = s2.y;
        }
        float qbh = 0.f;
        #pragma unroll
        for (int o = 0; o < 16; ++o) qbh += rq[o] * s_klb[o];
        qbv[h] = qbh;

        uint4* oq = (uint4*)(qrow + h * 16);
        uint4* ok = (uint4*)(kvrow + h * 16);
        uint4* ov = (uint4*)(kvrow + 64 + h * 16);
        oq[0] = pack8c(rqt); oq[1] = pack8c(rqt + 8);
        ok[0] = pack8c(rk);  ok[1] = pack8c(rk + 8);
        ov[0] = pack8c(rv);  ov[1] = pack8c(rv + 8);
    }
    *(float4*)(qrow + 64) = *(float4*)&qbv[0];
}

// ---------------- Hierarchical scan ----------------
__global__ __launch_bounds__(256) void scan_bsum_kernel(
    const int* __restrict__ counts, int* __restrict__ bsum)
{
    __shared__ int sd[256];
    int i = blockIdx.x * 256 + threadIdx.x;
    sd[threadIdx.x] = (i < NN) ? counts[i] : 0;
    __syncthreads();
    for (int s = 128; s > 0; s >>= 1) {
        if (threadIdx.x < (unsigned)s) sd[threadIdx.x] += sd[threadIdx.x + s];
        __syncthreads();
    }
    if (threadIdx.x == 0) bsum[blockIdx.x] = sd[0];
}

__global__ __launch_bounds__(256) void scan_top_kernel(int* __restrict__ bsum)
{
    __shared__ int tmp[256];
    int v = (threadIdx.x < NBLK) ? bsum[threadIdx.x] : 0;
    tmp[threadIdx.x] = v;
    __syncthreads();
    for (int d = 1; d < 256; d <<= 1) {
        int t = (threadIdx.x >= (unsigned)d) ? tmp[threadIdx.x - d] : 0;
        __syncthreads();
        tmp[threadIdx.x] += t;
        __syncthreads();
    }
    if (threadIdx.x < NBLK) bsum[threadIdx.x] = tmp[threadIdx.x] - v;  // exclusive
}

__global__ __launch_bounds__(256) void scan_final_kernel(
    const int* __restrict__ counts, const int* __restrict__ bsum,
    int* __restrict__ offsets)
{
    __shared__ int tmp[256];
    int i = blockIdx.x * 256 + threadIdx.x;
    int v = (i < NN) ? counts[i] : 0;
    tmp[threadIdx.x] = v;
    __syncthreads();
    for (int d = 1; d < 256; d <<= 1) {
        int t = (threadIdx.x >= (unsigned)d) ? tmp[threadIdx.x - d] : 0;
        __syncthreads();
        tmp[threadIdx.x] += t;
        __syncthreads();
    }
    int excl = tmp[threadIdx.x] - v + bsum[blockIdx.x];
    if (i < NN) offsets[i] = excl;
}

// ---------------- Kernel B: edge compute in ORIGINAL edge order ----------------
// ea/ei/rank all stream contiguously; CSR position = offsets[row] + rank[e]
// (offsets is a 200KB L2-resident table). Payload/wfac writes land at random CSR
// positions but each edge's 128B payload row is a full-line write.
// R4-verified MFMA structure: s_trA + s_trB, batched 4-tile loops, no barriers
// (per-wave private LDS rows, same-wave in-order DS pipe).
__global__ __launch_bounds__(256) void edge_compute_kernel(
    const int* __restrict__ ei, const int* __restrict__ rank,
    const int* __restrict__ offsets,
    const float* __restrict__ ea,
    const float* __restrict__ wkn_w1, const float* __restrict__ wkn_b1,
    const float* __restrict__ wkn_w2, const float* __restrict__ wkn_b2,
    const float* __restrict__ wvn_w1, const float* __restrict__ wvn_b1,
    const float* __restrict__ wvn_w2, const float* __restrict__ wvn_b2,
    const uint16_t* __restrict__ qtq, const uint16_t* __restrict__ hkv,
    uint16_t* __restrict__ payload, float* __restrict__ wfac)
{
    __shared__ uint16_t s_trA[4][64][24];
    __shared__ uint16_t s_trB[4][64][24];

    const int w = threadIdx.x >> 6;
    const int L = threadIdx.x & 63;
    const int m = L & 15;     // MFMA: A out-ch / B edge; tail: edge-within-tile
    const int g = L >> 4;     // MFMA: k-group; tail: head
    const int ebase = blockIdx.x * 256 + w * 64;

    // streaming per-edge metadata for the 4 tiles
    int rows[4], cols[4], posv[4];
    #pragma unroll
    for (int t = 0; t < 4; ++t) {
        const int e = ebase + 16 * t + m;
        rows[t] = ei[e];
        cols[t] = ei[NE + e];
    }
    #pragma unroll
    for (int t = 0; t < 4; ++t) {
        const int e = ebase + 16 * t + m;
        posv[t] = offsets[rows[t]] + rank[e];
    }

    // --- stage edge_attr B-fragments (CONTIGUOUS: 16 consecutive 128B rows/tile) ---
    bf8 eaf[4];
    #pragma unroll
    for (int t = 0; t < 4; ++t) {
        const float* er = ea + (size_t)(ebase + 16 * t + m) * ECH + 8 * g;
        eaf[t] = pack_bf8(*(const float4*)er, *(const float4*)(er + 4));
    }
    // --- weight A-fragments ---
    bf8 w1kf, w1vf, w2kf, w2vf;
    {
        const float* p = wkn_w1 + m * 32 + 8 * g;
        w1kf = pack_bf8(*(const float4*)p, *(const float4*)(p + 4));
        p = wvn_w1 + m * 32 + 8 * g;
        w1vf = pack_bf8(*(const float4*)p, *(const float4*)(p + 4));
        if (g < 2) {
            p = wkn_w2 + m * 16 + 8 * g;
            w2kf = pack_bf8(*(const float4*)p, *(const float4*)(p + 4));
            p = wvn_w2 + m * 16 + 8 * g;
            w2vf = pack_bf8(*(const float4*)p, *(const float4*)(p + 4));
        } else {
            w2kf = zero_bf8(); w2vf = zero_bf8();
        }
    }
    float4 b1k = *(const float4*)(wkn_b1 + 4 * g);
    float4 b1v = *(const float4*)(wvn_b1 + 4 * g);
    float4 b2k = *(const float4*)(wkn_b2 + 4 * g);
    float4 b2v = *(const float4*)(wvn_b2 + 4 * g);

    // --- layer1 k-net -> s_trA; read l1k ---
    #pragma unroll
    for (int t = 0; t < 4; ++t) {
        f32x4 acc = {b1k.x, b1k.y, b1k.z, b1k.w};
        acc = __builtin_amdgcn_mfma_f32_16x16x32_bf16(w1kf, eaf[t], acc, 0, 0, 0);
        uint2 pk;
        pk.x = cvt_pk_bf16(ssp_f(acc[0]), ssp_f(acc[1]));
        pk.y = cvt_pk_bf16(ssp_f(acc[2]), ssp_f(acc[3]));
        *(uint2*)&s_trA[w][16 * t + m][4 * g] = pk;
    }
    bf8 l1k[4];
    #pragma unroll
    for (int t = 0; t < 4; ++t)
        l1k[t] = (g < 2) ? *(const bf8*)&s_trA[w][16 * t + m][8 * g] : zero_bf8();
    // --- layer1 v-net -> s_trA (reuse); read l1v ---
    #pragma unroll
    for (int t = 0; t < 4; ++t) {
        f32x4 acc = {b1v.x, b1v.y, b1v.z, b1v.w};
        acc = __builtin_amdgcn_mfma_f32_16x16x32_bf16(w1vf, eaf[t], acc, 0, 0, 0);
        uint2 pk;
        pk.x = cvt_pk_bf16(ssp_f(acc[0]), ssp_f(acc[1]));
        pk.y = cvt_pk_bf16(ssp_f(acc[2]), ssp_f(acc[3]));
        *(uint2*)&s_trA[w][16 * t + m][4 * g] = pk;
    }
    bf8 l1v[4];
    #pragma unroll
    for (int t = 0; t < 4; ++t)
        l1v[t] = (g < 2) ? *(const bf8*)&s_trA[w][16 * t + m][8 * g] : zero_bf8();

    // --- layer2: Wk -> s_trB, Wv -> s_trA (batched over tiles, R4 structure) ---
    #pragma unroll
    for (int t = 0; t < 4; ++t) {
        f32x4 acc = {b2k.x, b2k.y, b2k.z, b2k.w};
        acc = __builtin_amdgcn_mfma_f32_16x16x32_bf16(w2kf, l1k[t], acc, 0, 0, 0);
        uint2 pk;
        pk.x = cvt_pk_bf16(acc[0], acc[1]);
        pk.y = cvt_pk_bf16(acc[2], acc[3]);
        *(uint2*)&s_trB[w][16 * t + m][4 * g] = pk;

        f32x4 accv = {b2v.x, b2v.y, b2v.z, b2v.w};
        accv = __builtin_amdgcn_mfma_f32_16x16x32_bf16(w2vf, l1v[t], accv, 0, 0, 0);
        uint2 pv;
        pv.x = cvt_pk_bf16(accv[0], accv[1]);
        pv.y = cvt_pk_bf16(accv[2], accv[3]);
        *(uint2*)&s_trA[w][16 * t + m][4 * g] = pv;
    }

    // --- tail: 4 lanes per edge. Lane (g,m) = head g of edge 16t+m. ---
    #pragma unroll
    for (int t = 0; t < 4; ++t) {
        const int row = rows[t], col = cols[t];

        uint32_t wk_u[8], wv_u[8];
        *(uint4*)&wk_u[0] = *(const uint4*)&s_trB[w][16 * t + m][0];
        *(uint4*)&wk_u[4] = *(const uint4*)&s_trB[w][16 * t + m][8];
        *(uint4*)&wv_u[0] = *(const uint4*)&s_trA[w][16 * t + m][0];
        *(uint4*)&wv_u[4] = *(const uint4*)&s_trA[w][16 * t + m][8];

        const uint16_t* qrow = qtq + (size_t)row * 72;
        const uint16_t* kvrow = hkv + (size_t)col * 128;
        uint32_t q_u[8], k_u[8], v_u[8];
        *(uint4*)&q_u[0] = *(const uint4*)(qrow + 16 * g);
        *(uint4*)&q_u[4] = *(const uint4*)(qrow + 16 * g + 8);
        *(uint4*)&k_u[0] = *(const uint4*)(kvrow + 16 * g);
        *(uint4*)&k_u[4] = *(const uint4*)(kvrow + 16 * g + 8);
        *(uint4*)&v_u[0] = *(const uint4*)(kvrow + 64 + 16 * g);
        *(uint4*)&v_u[4] = *(const uint4*)(kvrow + 64 + 16 * g + 8);

        v2f qk2 = {0.f, 0.f};
        #pragma unroll
        for (int i = 0; i < 8; ++i)
            qk2 += bfpair(q_u[i]) * (bfpair(wk_u[i]) * bfpair(k_u[i]));
        float qk = *(const float*)(qrow + 64 + 2 * g) + qk2.x + qk2.y;
        float wgt = __builtin_amdgcn_exp2f(qk);   // == exp(true logit)
        v2f wgt2 = {wgt, wgt};

        uint32_t po[8];
        #pragma unroll
        for (int i = 0; i < 8; ++i) {
            v2f o2 = (bfpair(wv_u[i]) * bfpair(v_u[i])) * wgt2;
            po[i] = cvt_pk_bf16(o2.x, o2.y);
        }
        uint4* pd = (uint4*)(payload + (size_t)posv[t] * HD + 16 * g);
        pd[0] = *(uint4*)&po[0];
        pd[1] = *(uint4*)&po[4];
        wfac[(size_t)posv[t] * NHEAD + g] = wgt;
    }
}

// ---------------- Kernel G: pure gather+normalize, one wave per node ----------------
// 50000 waves, zero LDS, full occupancy; CSR-contiguous payload streaming (unchanged).
__global__ __launch_bounds__(256) void gather_kernel(
    const uint16_t* __restrict__ payload, const float* __restrict__ wfac,
    const int* __restrict__ offsets, const int* __restrict__ counts,
    float* __restrict__ mout)
{
    const int n = (blockIdx.x * 256 + threadIdx.x) >> 6;   // one wave per node
    if (n >= NN) return;
    const int L = threadIdx.x & 63;
    const int q = L & 7;              // channel octet
    const int g = L >> 3;             // edge group 0..7
    const int h = q >> 1;             // head owning the octet

    const int st = offsets[n];
    const int deg = counts[n];

    v2f u2[4] = {{0.f,0.f},{0.f,0.f},{0.f,0.f},{0.f,0.f}};
    float ds = 0.f;
    const uint16_t* pp = payload + (size_t)st * HD + 8 * q;
    const float* wp = wfac + (size_t)st * NHEAD + h;
    const int iters = (deg + 7) >> 3;
    for (int i = 0; i < iters; i += 2) {
        // two independent 1KB wave-loads in flight per pass (R4-measured config)
        const int e0 = 8 * i + g;
        const int e1 = e0 + 8;
        if (e0 < deg) {
            uint4 pv = *(const uint4*)(pp + (size_t)e0 * HD);
            u2[0] += bfpair(pv.x); u2[1] += bfpair(pv.y);
            u2[2] += bfpair(pv.z); u2[3] += bfpair(pv.w);
            ds += wp[(size_t)e0 * NHEAD];
        }
        if (e1 < deg) {
            uint4 pv = *(const uint4*)(pp + (size_t)e1 * HD);
            u2[0] += bfpair(pv.x); u2[1] += bfpair(pv.y);
            u2[2] += bfpair(pv.z); u2[3] += bfpair(pv.w);
            ds += wp[(size_t)e1 * NHEAD];
        }
    }
    // reduce over the 8 edge-groups (xor lane bits 3,4,5)
    #pragma unroll
    for (int s = 8; s < 64; s <<= 1) {
        #pragma unroll
        for (int j = 0; j < 4; ++j) {
            u2[j].x += __shfl_xor(u2[j].x, s);
            u2[j].y += __shfl_xor(u2[j].y, s);
        }
        ds += __shfl_xor(ds, s);
    }
    if (g == 0) {
        float inv = (deg > 0) ? (1.f / ds) : 0.f;
        float r0[4] = {u2[0].x * inv, u2[0].y * inv, u2[1].x * inv, u2[1].y * inv};
        float r1[4] = {u2[2].x * inv, u2[2].y * inv, u2[3].x * inv, u2[3].y * inv};
        float* mr = mout + (size_t)n * HD + 8 * q;
        *(float4*)mr = *(float4*)r0;
        *(float4*)(mr + 4) = *(float4*)r1;
    }
}

// ---------------- Kernel F: dense finalize (wvl + cen + ssp + out) ----------------
__global__ __launch_bounds__(256) void finalize_kernel(
    const float* __restrict__ x, const float* __restrict__ m,
    const int* __restrict__ counts,
    const float* __restrict__ wvl_w, const float* __restrict__ wvl_b,
    const float* __restrict__ cen_w, const float* __restrict__ cen_b,
    const float* __restrict__ out_w, const float* __restrict__ out_b,
    float* __restrict__ out)
{
    __shared__ float s_cw[4096], s_ow[4096];
    __shared__ float s_x[4][64], s_m[4][64], s_t[4][64];
    for (int idx = threadIdx.x; idx < 4096; idx += 256) {
        int o = idx & 63, i = idx >> 6;
        s_cw[i * 64 + o] = cen_w[o * 64 + i];
        s_ow[i * 64 + o] = out_w[o * 64 + i];
    }
    __syncthreads();

    const int l = threadIdx.x >> 6;   // wave id
    const int c = threadIdx.x & 63;   // lane = output channel
    const int hh = c >> 4;

    // hoisted per-lane constants (channel is fixed per lane)
    float wvlr[16];
    #pragma unroll
    for (int i = 0; i < 16; ++i) wvlr[i] = wvl_w[(c & 15) * 16 + i];
    const float vlb = wvl_b[c & 15];
    const float cb = cen_b[c];
    const float ob = out_b[c];

    const int n0 = blockIdx.x * 64 + l * 16;
    for (int t = 0; t < 16; ++t) {
        const int n = n0 + t;
        const bool valid = n < NN;
        const int deg = valid ? counts[n] : 0;
        s_x[l][c] = valid ? x[(size_t)n * HD + c] : 0.f;
        s_m[l][c] = valid ? m[(size_t)n * HD + c] : 0.f;
        // s_x/s_m/s_t rows are same-wave private: no __syncthreads needed

        float aggr = 0.f;
        if (deg > 0) {
            float s = vlb;
            #pragma unroll
            for (int i = 0; i < 16; ++i) s += s_m[l][hh * 16 + i] * wvlr[i];
            aggr = s;
        }
        float sc = cb;
        #pragma unroll 8
        for (int i = 0; i < 64; ++i) sc += s_x[l][i] * s_cw[i * 64 + c];
        sc += aggr;
        s_t[l][c] = ssp_f(sc);
        float so = ob;
        #pragma unroll 8
        for (int i = 0; i < 64; ++i) so += s_t[l][i] * s_ow[i * 64 + c];
        if (valid) out[(size_t)n * HD + c] = so;
    }
}

extern "C" void kernel_launch(void* const* d_in, const int* in_sizes, int n_in,
                              void* d_out, int out_size, void* d_ws, size_t ws_size,
                              hipStream_t stream)
{
    const float* x      = (const float*)d_in[0];
    const int*   ei     = (const int*)d_in[1];
    const float* ea     = (const float*)d_in[2];
    const float* k_w    = (const float*)d_in[3];
    const float* q_w    = (const float*)d_in[4];
    const float* v_w    = (const float*)d_in[5];
    const float* wkn_w1 = (const float*)d_in[6];
    const float* wkn_b1 = (const float*)d_in[7];
    const float* wkn_w2 = (const float*)d_in[8];
    const float* wkn_b2 = (const float*)d_in[9];
    const float* wkl_w  = (const float*)d_in[10];
    const float* wkl_b  = (const float*)d_in[11];
    const float* wvn_w1 = (const float*)d_in[12];
    const float* wvn_b1 = (const float*)d_in[13];
    const float* wvn_w2 = (const float*)d_in[14];
    const float* wvn_b2 = (const float*)d_in[15];
    const float* wvl_w  = (const float*)d_in[16];
    const float* wvl_b  = (const float*)d_in[17];
    const float* cen_w  = (const float*)d_in[18];
    const float* cen_b  = (const float*)d_in[19];
    const float* out_w  = (const float*)d_in[20];
    const float* out_b  = (const float*)d_in[21];
    float* out = (float*)d_out;

    // workspace layout
    float* wfac  = (float*)d_ws;                              // NE*4 f32
    uint16_t* qtq = (uint16_t*)(wfac + (size_t)NE * NHEAD);   // NN*72 (qt bf16 | qb f32)
    uint16_t* hkv = qtq + (size_t)NN * 72;                    // NN*128 (k|v bf16)
    uint16_t* payload = hkv + (size_t)NN * 128;               // NE*64 bf16
    int* rank    = (int*)(payload + (size_t)NE * HD);         // NE (rank within row)
    int* counts  = rank + NE;                                 // NN
    int* bsum    = counts + NN;                               // 256
    int* offsets = bsum + 256;                                // NN
    // m buffer aliases hkv (dead after edge_compute; NN*128 u16 == NN*64 f32)
    float* mbuf  = (float*)hkv;

    hipMemsetAsync(counts, 0, (size_t)NN * sizeof(int), stream);
    node_count_kernel<<<NEBLK, 256, 0, stream>>>(
        x, ei, k_w, q_w, v_w, wkl_w, wkl_b, qtq, hkv, counts, rank);
    scan_bsum_kernel<<<NBLK, 256, 0, stream>>>(counts, bsum);
    scan_top_kernel<<<1, 256, 0, stream>>>(bsum);
    scan_final_kernel<<<NBLK, 256, 0, stream>>>(counts, bsum, offsets);
    edge_compute_kernel<<<NEBLK, 256, 0, stream>>>(
        ei, rank, offsets, ea, wkn_w1, wkn_b1, wkn_w2, wkn_b2,
        wvn_w1, wvn_b1, wvn_w2, wvn_b2,
        qtq, hkv, payload, wfac);
    gather_kernel<<<(NN * 64) / 256, 256, 0, stream>>>(
        payload, wfac, offsets, counts, mbuf);
    finalize_kernel<<<(NN + 63) / 64, 256, 0, stream>>>(
        x, mbuf, counts, wvl_w, wvl_b, cen_w, cen_b, out_w, out_b, out);
}